// Round 1
// baseline (604.788 us; speedup 1.0000x reference)
//
#include <hip/hip_runtime.h>
#include <hip/hip_bf16.h>
#include <stdint.h>

#define B_ 128
#define L_ 512
#define V_ 256
#define E_ 64
#define H_ 256

typedef __attribute__((ext_vector_type(8))) __bf16 bf16x8;
typedef __attribute__((ext_vector_type(4))) float f32x4;
typedef __attribute__((ext_vector_type(8))) unsigned short ushort8;

__device__ __forceinline__ unsigned short f2bf(float f) {
    unsigned int u = __builtin_bit_cast(unsigned int, f);
    u += 0x7fffu + ((u >> 16) & 1u);           // RNE
    return (unsigned short)(u >> 16);
}

// XOR swizzle: element (row, byte-in-row) of a [rows][256] bf16 tile.
// Spreads the 512B row stride across banks; read side uses 16B-aligned bases
// so the XOR (bits 4..6) commutes with the low 4 bits.
__device__ __forceinline__ unsigned swzoff(unsigned row, unsigned inrow) {
    return (row * 512u + inrow) ^ ((row & 7u) << 4);
}

// ---------------- prologue: embW2 = emb@W_xh + b_h ; W_hy->bf16 ; bias ----
__global__ void prologue_kernel(const float* __restrict__ emb,
                                const float* __restrict__ Wxh,
                                const float* __restrict__ bh,
                                const float* __restrict__ Why,
                                const float* __restrict__ Whyb,
                                const float* __restrict__ by,
                                float* __restrict__ embW2,
                                unsigned short* __restrict__ whyb16,
                                float* __restrict__ bias)
{
    int blk = blockIdx.x, tid = threadIdx.x;
    if (blk < V_) {
        float s = bh[tid];
        #pragma unroll 8
        for (int e = 0; e < E_; ++e)
            s = fmaf(emb[blk * E_ + e], Wxh[e * H_ + tid], s);
        embW2[blk * H_ + tid] = s;
    } else if (blk < 2 * V_) {
        int i = (blk - V_) * 256 + tid;
        whyb16[i] = f2bf(Why[i]);
    } else {
        bias[tid] = Whyb[tid] + by[tid];
    }
}

// ---------------- recurrence: 8 blocks x 16 batch rows, 512 steps ---------
__global__ __launch_bounds__(256, 1) void rnn_rec_kernel(
    const int* __restrict__ x, const float* __restrict__ hidden,
    const float* __restrict__ embW2, const float* __restrict__ Whh,
    unsigned short* __restrict__ hs, float* __restrict__ hfin)
{
    __shared__ unsigned short h_lds[2][16 * 256];   // swizzled bf16, dbuf

    const int tid = threadIdx.x;
    const int w = tid >> 6, lane = tid & 63;
    const int l15 = lane & 15, lhi = lane >> 4;
    const int b0 = blockIdx.x * 16;
    const int row_base = lhi * 4;                   // + r -> C/D row (m89)

    int col[4];
    #pragma unroll
    for (int n = 0; n < 4; ++n) col[n] = w * 64 + n * 16 + l15;

    // persistent W_hh B-fragments: B[k][col], k = kt*32 + lhi*8 + j
    bf16x8 bfrag[4][8];
    #pragma unroll
    for (int n = 0; n < 4; ++n) {
        #pragma unroll
        for (int kt = 0; kt < 8; ++kt) {
            ushort8 tv;
            #pragma unroll
            for (int j = 0; j < 8; ++j) {
                int k = kt * 32 + lhi * 8 + j;
                tv[j] = f2bf(Whh[k * H_ + col[n]]);
            }
            bfrag[n][kt] = __builtin_bit_cast(bf16x8, tv);
        }
    }

    // init h buffer 0 from `hidden`
    for (int i = tid; i < 16 * 256; i += 256) {
        int row = i >> 8, c = i & 255;
        *(unsigned short*)((char*)h_lds[0] + swzoff(row, c * 2)) =
            f2bf(hidden[(b0 + row) * H_ + c]);
    }

    // software-pipelined embW2 gather state (named double buffers, rule #20)
    float ewA[4][4], ewB[4][4];
    int   xvA[4], xvB[4];
    #pragma unroll
    for (int r = 0; r < 4; ++r) xvA[r] = x[(b0 + row_base + r) * L_ + 0];
    #pragma unroll
    for (int n = 0; n < 4; ++n)
        #pragma unroll
        for (int r = 0; r < 4; ++r)
            ewA[n][r] = embW2[xvA[r] * H_ + col[n]];
    #pragma unroll
    for (int r = 0; r < 4; ++r) xvB[r] = x[(b0 + row_base + r) * L_ + 1];

    __syncthreads();

    // one step: ec = gathered embW2 for step t; en = buffer to gather t+1
    // xg = x values for t+1 (used for gather); xf = refill with x(t+2); cb = LDS buf
    auto step = [&](int t, float (&ec)[4][4], float (&en)[4][4],
                    int (&xg)[4], int (&xf)[4], int cb) {
        f32x4 acc[4];
        #pragma unroll
        for (int n = 0; n < 4; ++n) {
            acc[n][0] = ec[n][0]; acc[n][1] = ec[n][1];
            acc[n][2] = ec[n][2]; acc[n][3] = ec[n][3];
        }
        // issue next-step gather early (hidden under MFMA chain)
        #pragma unroll
        for (int n = 0; n < 4; ++n)
            #pragma unroll
            for (int r = 0; r < 4; ++r)
                en[n][r] = embW2[xg[r] * H_ + col[n]];
        int t2 = t + 2; if (t2 > L_ - 1) t2 = L_ - 1;
        #pragma unroll
        for (int r = 0; r < 4; ++r) xf[r] = x[(b0 + row_base + r) * L_ + t2];

        // z += h @ W_hh   (A: row = l15, k-slot = lhi; swizzled ds_read_b128)
        #pragma unroll
        for (int kt = 0; kt < 8; ++kt) {
            unsigned off = swzoff((unsigned)l15, (unsigned)(kt * 64 + lhi * 16));
            bf16x8 a = *(const bf16x8*)((const char*)h_lds[cb] + off);
            #pragma unroll
            for (int n = 0; n < 4; ++n)
                acc[n] = __builtin_amdgcn_mfma_f32_16x16x32_bf16(
                             a, bfrag[n][kt], acc[n], 0, 0, 0);
        }

        // tanh, write h to next LDS buf (bf16) + hs (bf16) + final (f32)
        #pragma unroll
        for (int n = 0; n < 4; ++n) {
            #pragma unroll
            for (int r = 0; r < 4; ++r) {
                float z = acc[n][r];
                float e = __expf(2.0f * z);
                float th = 1.0f - 2.0f * __builtin_amdgcn_rcpf(e + 1.0f);
                unsigned short hb = f2bf(th);
                int row = row_base + r;
                hs[((size_t)(b0 + row) * L_ + t) * H_ + col[n]] = hb;
                *(unsigned short*)((char*)h_lds[cb ^ 1] +
                    swzoff((unsigned)row, (unsigned)(col[n] * 2))) = hb;
                if (t == L_ - 1)
                    hfin[(b0 + row) * H_ + col[n]] = th;
            }
        }
        __syncthreads();
    };

    for (int t = 0; t < L_; t += 2) {
        step(t,     ewA, ewB, xvB, xvA, 0);
        step(t + 1, ewB, ewA, xvA, xvB, 1);
    }
}

// ---------------- logits: hs[65536,256] @ W_hy^T + bias -------------------
__global__ __launch_bounds__(256, 1) void logits_kernel(
    const unsigned short* __restrict__ hs,
    const unsigned short* __restrict__ whyb16,
    const float* __restrict__ bias,
    float* __restrict__ logits)
{
    __shared__ unsigned short a_lds[2][32 * 256];   // 2 x 16KB, swizzled

    const int tid = threadIdx.x;
    const int w = tid >> 6, lane = tid & 63;
    const int l15 = lane & 15, lhi = lane >> 4;
    const size_t rowblk = (size_t)blockIdx.x * 256;

    int col[4];
    #pragma unroll
    for (int n = 0; n < 4; ++n) col[n] = w * 64 + n * 16 + l15;

    // W_hy^T fragments: B[k=h][col=v] = W_hy[v][h] (contiguous in h -> b128)
    bf16x8 bfrag[4][8];
    #pragma unroll
    for (int n = 0; n < 4; ++n)
        #pragma unroll
        for (int kt = 0; kt < 8; ++kt)
            bfrag[n][kt] = *(const bf16x8*)(whyb16 + col[n] * H_ + kt * 32 + lhi * 8);

    float bv[4];
    #pragma unroll
    for (int n = 0; n < 4; ++n) bv[n] = bias[col[n]];

    // stage chunk 0 (32 rows) into buf 0, swizzled
    #pragma unroll
    for (int ii = 0; ii < 4; ++ii) {
        unsigned Lg = (unsigned)(ii * 256 + tid) * 16u;
        unsigned row = Lg >> 9, inrow = Lg & 511u;
        ushort8 v = *(const ushort8*)((const char*)hs +
                     ((rowblk + row) * 512u + inrow));
        *(ushort8*)((char*)a_lds[0] + swzoff(row, inrow)) = v;
    }
    __syncthreads();

    for (int c = 0; c < 8; ++c) {
        const int cb = c & 1;
        // T14: issue next chunk's global loads early, LDS-write late
        ushort8 vs[4];
        unsigned sr0, sr1, sr2, sr3, si0, si1, si2, si3;
        unsigned srow[4], sinrow[4];
        if (c < 7) {
            #pragma unroll
            for (int ii = 0; ii < 4; ++ii) {
                unsigned Lg = (unsigned)(ii * 256 + tid) * 16u;
                srow[ii] = Lg >> 9; sinrow[ii] = Lg & 511u;
                vs[ii] = *(const ushort8*)((const char*)hs +
                          ((rowblk + (size_t)(c + 1) * 32 + srow[ii]) * 512u + sinrow[ii]));
            }
        }
        (void)sr0;(void)sr1;(void)sr2;(void)sr3;(void)si0;(void)si1;(void)si2;(void)si3;

        #pragma unroll
        for (int m = 0; m < 2; ++m) {
            f32x4 acc[4];
            #pragma unroll
            for (int n = 0; n < 4; ++n) acc[n] = f32x4{0.f, 0.f, 0.f, 0.f};
            #pragma unroll
            for (int kt = 0; kt < 8; ++kt) {
                unsigned rl = (unsigned)(m * 16 + l15);
                bf16x8 a = *(const bf16x8*)((const char*)a_lds[cb] +
                            swzoff(rl, (unsigned)(kt * 64 + lhi * 16)));
                #pragma unroll
                for (int n = 0; n < 4; ++n)
                    acc[n] = __builtin_amdgcn_mfma_f32_16x16x32_bf16(
                                 a, bfrag[n][kt], acc[n], 0, 0, 0);
            }
            size_t grow = rowblk + (size_t)c * 32 + m * 16 + lhi * 4;
            #pragma unroll
            for (int n = 0; n < 4; ++n)
                #pragma unroll
                for (int r = 0; r < 4; ++r)
                    logits[(grow + r) * V_ + col[n]] = acc[n][r] + bv[n];
        }
        if (c < 7) {
            #pragma unroll
            for (int ii = 0; ii < 4; ++ii)
                *(ushort8*)((char*)a_lds[cb ^ 1] + swzoff(srow[ii], sinrow[ii])) = vs[ii];
        }
        __syncthreads();
    }
}

extern "C" void kernel_launch(void* const* d_in, const int* in_sizes, int n_in,
                              void* d_out, int out_size, void* d_ws, size_t ws_size,
                              hipStream_t stream) {
    const int*   x      = (const int*)d_in[0];
    const float* hidden = (const float*)d_in[1];
    const float* emb    = (const float*)d_in[2];
    const float* Wxh    = (const float*)d_in[3];
    const float* Whh    = (const float*)d_in[4];
    const float* bh     = (const float*)d_in[5];
    const float* Why    = (const float*)d_in[6];
    const float* Whyb   = (const float*)d_in[7];
    const float* by     = (const float*)d_in[8];

    float* out = (float*)d_out;
    char*  ws  = (char*)d_ws;

    unsigned short* hs     = (unsigned short*)ws;                  // 33,554,432 B
    float*          embW2  = (float*)(ws + 33554432);              //    262,144 B
    unsigned short* whyb16 = (unsigned short*)(ws + 33816576);     //    131,072 B
    float*          bias   = (float*)(ws + 33947648);              //      1,024 B

    prologue_kernel<<<2 * V_ + 1, 256, 0, stream>>>(emb, Wxh, bh, Why, Whyb, by,
                                                    embW2, whyb16, bias);
    rnn_rec_kernel<<<B_ / 16, 256, 0, stream>>>(x, hidden, embW2, Whh,
                                                hs, out + (size_t)B_ * L_ * V_);
    logits_kernel<<<(B_ * L_) / 256, 256, 0, stream>>>(hs, whyb16, bias, out);
}

// Round 2
// 503.685 us; speedup vs baseline: 1.2007x; 1.2007x over previous
//
#include <hip/hip_runtime.h>
#include <hip/hip_bf16.h>
#include <stdint.h>

#define B_ 128
#define L_ 512
#define V_ 256
#define E_ 64
#define H_ 256

typedef __attribute__((ext_vector_type(8))) __bf16 bf16x8;
typedef __attribute__((ext_vector_type(4))) float f32x4;
typedef __attribute__((ext_vector_type(8))) unsigned short ushort8;

__device__ __forceinline__ unsigned short f2bf(float f) {
    unsigned int u = __builtin_bit_cast(unsigned int, f);
    u += 0x7fffu + ((u >> 16) & 1u);           // RNE
    return (unsigned short)(u >> 16);
}

__device__ __forceinline__ unsigned pack2bf(float a, float b) {
    return (unsigned)f2bf(a) | ((unsigned)f2bf(b) << 16);
}

// swizzled byte offset into a [16][256] bf16 LDS tile:
// addr = row*512 + (inrow_bytes ^ ((row&7)<<4))
// (row*512 has no bits <9, so XOR never interacts with the row term)

// ---------------- prologue: embW2 = emb@W_xh + b_h ; casts; bias ----------
__global__ void prologue_kernel(const float* __restrict__ emb,
                                const float* __restrict__ Wxh,
                                const float* __restrict__ bh,
                                const float* __restrict__ Why,
                                const float* __restrict__ Whyb,
                                const float* __restrict__ by,
                                const float* __restrict__ Whh,
                                float* __restrict__ embW2,
                                unsigned short* __restrict__ whyb16,
                                float* __restrict__ bias,
                                unsigned short* __restrict__ whhT16)
{
    int blk = blockIdx.x, tid = threadIdx.x;
    if (blk < V_) {
        float s = bh[tid];
        #pragma unroll 8
        for (int e = 0; e < E_; ++e)
            s = fmaf(emb[blk * E_ + e], Wxh[e * H_ + tid], s);
        embW2[blk * H_ + tid] = s;
    } else if (blk < 2 * V_) {
        int i = (blk - V_) * 256 + tid;
        whyb16[i] = f2bf(Why[i]);
    } else if (blk == 2 * V_) {
        bias[tid] = Whyb[tid] + by[tid];
    } else {
        int c = blk - (2 * V_ + 1);                 // hcol
        whhT16[c * H_ + tid] = f2bf(Whh[tid * H_ + c]);   // W_hh^T[c][k]
    }
}

// ---------------- recurrence: 8 blocks x 16 batch rows, 512 steps ---------
// Transposed GEMM: z^T = W_hh^T (A) x h^T (B).
// D layout (m89): lane(lhi,l15) holds z[batch=l15][hcol = hb + lhi*4 + r].
__global__ __launch_bounds__(512, 1) void rnn_rec_kernel(
    const int* __restrict__ x, const float* __restrict__ hidden,
    const float* __restrict__ embW2, const unsigned short* __restrict__ whhT16,
    unsigned short* __restrict__ hs, float* __restrict__ hfin)
{
    __shared__ unsigned short h_lds[2][16 * 256];   // swizzled bf16, dbuf

    const int tid  = threadIdx.x;
    const int w    = tid >> 6, lane = tid & 63;
    const int l15  = lane & 15, lhi = lane >> 4;
    const int lhi4 = lhi * 4;
    const int b0   = blockIdx.x * 16;
    const int hb0  = w * 32, hb1 = w * 32 + 16;
    const unsigned swzm = (unsigned)((l15 & 7) << 4);
    const int xrow = (b0 + l15) * L_;

    // persistent A-fragments: A[row=l15][k=lhi*8+j] = W_hh^T[hb+l15][kt*32+lhi*8+j]
    bf16x8 afrag0[8], afrag1[8];
    #pragma unroll
    for (int kt = 0; kt < 8; ++kt) {
        afrag0[kt] = *(const bf16x8*)(whhT16 + (hb0 + l15) * H_ + kt * 32 + lhi * 8);
        afrag1[kt] = *(const bf16x8*)(whhT16 + (hb1 + l15) * H_ + kt * 32 + lhi * 8);
    }

    // init h buffer 0 from `hidden` (swizzled)
    for (int i = tid; i < 16 * 256; i += 512) {
        int row = i >> 8, c = i & 255;
        *(unsigned short*)((char*)h_lds[0] +
            (row * 512 + ((c * 2) ^ ((row & 7) << 4)))) =
            f2bf(hidden[(b0 + row) * H_ + c]);
    }

    // software-pipelined gather state (named double buffers)
    int xvA = x[xrow + 0];
    f32x4 eA0 = *(const f32x4*)(embW2 + xvA * H_ + hb0 + lhi4);
    f32x4 eA1 = *(const f32x4*)(embW2 + xvA * H_ + hb1 + lhi4);
    int xvB = x[xrow + 1];
    f32x4 eB0, eB1;

    __syncthreads();

    auto tanhpack = [&](f32x4 a, f32x4& th) -> uint2 {
        #pragma unroll
        for (int r = 0; r < 4; ++r) {
            float e = __builtin_exp2f(a[r] * 2.885390081777927f);   // e^{2z}
            th[r] = 1.0f - 2.0f * __builtin_amdgcn_rcpf(e + 1.0f);
        }
        uint2 p;
        p.x = pack2bf(th[0], th[1]);
        p.y = pack2bf(th[2], th[3]);
        return p;
    };

    // one step; ec* = this step's xW; en* = gather target for t+1 (uses xg);
    // xf refilled with x[t+2]; cb = LDS buffer holding h(t)
    auto step = [&](int t, f32x4& ec0, f32x4& ec1, f32x4& en0, f32x4& en1,
                    int xg, int& xf, int cb) {
        f32x4 acc0 = ec0, acc1 = ec1;
        // issue next-step gathers early (hide under MFMA + tanh)
        en0 = *(const f32x4*)(embW2 + xg * H_ + hb0 + lhi4);
        en1 = *(const f32x4*)(embW2 + xg * H_ + hb1 + lhi4);
        int t2 = t + 2; if (t2 > L_ - 1) t2 = L_ - 1;
        xf = x[xrow + t2];

        // z^T += W_hh^T @ h^T : B[k][col=batch=l15], k-slot = lhi (b128 reads)
        #pragma unroll
        for (int kt = 0; kt < 8; ++kt) {
            bf16x8 hv = *(const bf16x8*)((const char*)h_lds[cb] +
                         (l15 * 512 + (unsigned)((kt * 64 + lhi * 16) ^ swzm)));
            acc0 = __builtin_amdgcn_mfma_f32_16x16x32_bf16(afrag0[kt], hv, acc0, 0, 0, 0);
            acc1 = __builtin_amdgcn_mfma_f32_16x16x32_bf16(afrag1[kt], hv, acc1, 0, 0, 0);
        }

        f32x4 th0, th1;
        uint2 p0 = tanhpack(acc0, th0);
        uint2 p1 = tanhpack(acc1, th1);

        // h -> other LDS buffer (b64, swizzled): 4 consecutive hcols per lane
        *(uint2*)((char*)h_lds[cb ^ 1] +
            (l15 * 512 + (unsigned)((hb0 * 2 + lhi * 8) ^ swzm))) = p0;
        *(uint2*)((char*)h_lds[cb ^ 1] +
            (l15 * 512 + (unsigned)((hb1 * 2 + lhi * 8) ^ swzm))) = p1;

        // hs[b][t][h] bf16 (8B stores, fire-and-forget — never drained)
        size_t so = ((size_t)(b0 + l15) * L_ + t) * H_;
        *(uint2*)(hs + so + hb0 + lhi4) = p0;
        *(uint2*)(hs + so + hb1 + lhi4) = p1;

        if (t == L_ - 1) {
            *(f32x4*)(hfin + (b0 + l15) * H_ + hb0 + lhi4) = th0;
            *(f32x4*)(hfin + (b0 + l15) * H_ + hb1 + lhi4) = th1;
        }

        // LDS-only barrier: ds ops drained, global stores stay in flight
        __builtin_amdgcn_sched_barrier(0);
        asm volatile("s_waitcnt lgkmcnt(0)" ::: "memory");
        __builtin_amdgcn_s_barrier();
        __builtin_amdgcn_sched_barrier(0);
    };

    for (int t = 0; t < L_; t += 2) {
        step(t,     eA0, eA1, eB0, eB1, xvB, xvA, 0);
        step(t + 1, eB0, eB1, eA0, eA1, xvA, xvB, 1);
    }
}

// ---------------- logits: hs[65536,256] @ W_hy^T + bias -------------------
__global__ __launch_bounds__(256, 1) void logits_kernel(
    const unsigned short* __restrict__ hs,
    const unsigned short* __restrict__ whyb16,
    const float* __restrict__ bias,
    float* __restrict__ logits)
{
    __shared__ unsigned short a_lds[2][32 * 256];   // 2 x 16KB, swizzled

    const int tid = threadIdx.x;
    const int w = tid >> 6, lane = tid & 63;
    const int l15 = lane & 15, lhi = lane >> 4;
    const size_t rowblk = (size_t)blockIdx.x * 256;

    int col[4];
    #pragma unroll
    for (int n = 0; n < 4; ++n) col[n] = w * 64 + n * 16 + l15;

    bf16x8 bfrag[4][8];
    #pragma unroll
    for (int n = 0; n < 4; ++n)
        #pragma unroll
        for (int kt = 0; kt < 8; ++kt)
            bfrag[n][kt] = *(const bf16x8*)(whyb16 + col[n] * H_ + kt * 32 + lhi * 8);

    float bv[4];
    #pragma unroll
    for (int n = 0; n < 4; ++n) bv[n] = bias[col[n]];

    auto swz = [](unsigned row, unsigned inrow) -> unsigned {
        return row * 512u + (inrow ^ ((row & 7u) << 4));
    };

    #pragma unroll
    for (int ii = 0; ii < 4; ++ii) {
        unsigned Lg = (unsigned)(ii * 256 + tid) * 16u;
        unsigned row = Lg >> 9, inrow = Lg & 511u;
        ushort8 v = *(const ushort8*)((const char*)hs +
                     ((rowblk + row) * 512u + inrow));
        *(ushort8*)((char*)a_lds[0] + swz(row, inrow)) = v;
    }
    __syncthreads();

    for (int c = 0; c < 8; ++c) {
        const int cb = c & 1;
        ushort8 vs[4];
        unsigned srow[4], sinrow[4];
        if (c < 7) {
            #pragma unroll
            for (int ii = 0; ii < 4; ++ii) {
                unsigned Lg = (unsigned)(ii * 256 + tid) * 16u;
                srow[ii] = Lg >> 9; sinrow[ii] = Lg & 511u;
                vs[ii] = *(const ushort8*)((const char*)hs +
                          ((rowblk + (size_t)(c + 1) * 32 + srow[ii]) * 512u + sinrow[ii]));
            }
        }

        #pragma unroll
        for (int m = 0; m < 2; ++m) {
            f32x4 acc[4];
            #pragma unroll
            for (int n = 0; n < 4; ++n) acc[n] = f32x4{0.f, 0.f, 0.f, 0.f};
            #pragma unroll
            for (int kt = 0; kt < 8; ++kt) {
                unsigned rl = (unsigned)(m * 16 + l15);
                bf16x8 a = *(const bf16x8*)((const char*)a_lds[cb] +
                            swz(rl, (unsigned)(kt * 64 + lhi * 16)));
                #pragma unroll
                for (int n = 0; n < 4; ++n)
                    acc[n] = __builtin_amdgcn_mfma_f32_16x16x32_bf16(
                                 a, bfrag[n][kt], acc[n], 0, 0, 0);
            }
            size_t grow = rowblk + (size_t)c * 32 + m * 16 + lhi * 4;
            #pragma unroll
            for (int n = 0; n < 4; ++n)
                #pragma unroll
                for (int r = 0; r < 4; ++r)
                    logits[(grow + r) * V_ + col[n]] = acc[n][r] + bv[n];
        }
        if (c < 7) {
            #pragma unroll
            for (int ii = 0; ii < 4; ++ii)
                *(ushort8*)((char*)a_lds[cb ^ 1] + swz(srow[ii], sinrow[ii])) = vs[ii];
        }
        __syncthreads();
    }
}

extern "C" void kernel_launch(void* const* d_in, const int* in_sizes, int n_in,
                              void* d_out, int out_size, void* d_ws, size_t ws_size,
                              hipStream_t stream) {
    const int*   x      = (const int*)d_in[0];
    const float* hidden = (const float*)d_in[1];
    const float* emb    = (const float*)d_in[2];
    const float* Wxh    = (const float*)d_in[3];
    const float* Whh    = (const float*)d_in[4];
    const float* bh     = (const float*)d_in[5];
    const float* Why    = (const float*)d_in[6];
    const float* Whyb   = (const float*)d_in[7];
    const float* by     = (const float*)d_in[8];

    float* out = (float*)d_out;
    char*  ws  = (char*)d_ws;

    unsigned short* hs     = (unsigned short*)ws;                  // 33,554,432 B
    float*          embW2  = (float*)(ws + 33554432);              //    262,144 B
    unsigned short* whyb16 = (unsigned short*)(ws + 33816576);     //    131,072 B
    float*          bias   = (float*)(ws + 33947648);              //      1,024 B
    unsigned short* whhT16 = (unsigned short*)(ws + 33948672);     //    131,072 B

    prologue_kernel<<<2 * V_ + 1 + V_, 256, 0, stream>>>(emb, Wxh, bh, Why, Whyb, by, Whh,
                                                         embW2, whyb16, bias, whhT16);
    rnn_rec_kernel<<<B_ / 16, 512, 0, stream>>>(x, hidden, embW2, whhT16,
                                                hs, out + (size_t)B_ * L_ * V_);
    logits_kernel<<<(B_ * L_) / 256, 256, 0, stream>>>(hs, whyb16, bias, out);
}

// Round 3
// 485.273 us; speedup vs baseline: 1.2463x; 1.0379x over previous
//
#include <hip/hip_runtime.h>
#include <hip/hip_bf16.h>
#include <stdint.h>

#define B_ 128
#define L_ 512
#define V_ 256
#define E_ 64
#define H_ 256
#define SC 2.885390081777927f   // 2*log2(e): exp2(SC*z) = e^{2z}

typedef __attribute__((ext_vector_type(8))) __bf16 bf16x8;
typedef __attribute__((ext_vector_type(4))) float f32x4;
typedef __attribute__((ext_vector_type(8))) unsigned short ushort8;

__device__ __forceinline__ unsigned short f2bf(float f) {
    unsigned int u = __builtin_bit_cast(unsigned int, f);
    u += 0x7fffu + ((u >> 16) & 1u);           // RNE
    return (unsigned short)(u >> 16);
}

// ---------------- prologue: embW2 = SC*(emb@W_xh + b_h) ; casts; bias -----
__global__ void prologue_kernel(const float* __restrict__ emb,
                                const float* __restrict__ Wxh,
                                const float* __restrict__ bh,
                                const float* __restrict__ Why,
                                const float* __restrict__ Whyb,
                                const float* __restrict__ by,
                                const float* __restrict__ Whh,
                                float* __restrict__ embW2,
                                unsigned short* __restrict__ whyb16,
                                float* __restrict__ bias,
                                unsigned short* __restrict__ whhT16)
{
    int blk = blockIdx.x, tid = threadIdx.x;
    if (blk < V_) {
        float s = bh[tid];
        #pragma unroll 8
        for (int e = 0; e < E_; ++e)
            s = fmaf(emb[blk * E_ + e], Wxh[e * H_ + tid], s);
        embW2[blk * H_ + tid] = s * SC;
    } else if (blk < 2 * V_) {
        int i = (blk - V_) * 256 + tid;
        whyb16[i] = f2bf(Why[i]);
    } else if (blk == 2 * V_) {
        bias[tid] = Whyb[tid] + by[tid];
    } else {
        int c = blk - (2 * V_ + 1);                       // hcol
        whhT16[c * H_ + tid] = f2bf(Whh[tid * H_ + c] * SC);  // SC*W_hh^T
    }
}

// ---------------- recurrence: 8 blocks x 16 batch rows, 512 steps ---------
// z^T = (SC*W_hh^T) @ h^T ; D: lane(lhi,l15) -> batch=l15, hcol=hb+lhi*4+r
__global__ __launch_bounds__(512, 1) void rnn_rec_kernel(
    const int* __restrict__ x, const float* __restrict__ hidden,
    const float* __restrict__ embW2, const unsigned short* __restrict__ whhT16,
    unsigned short* __restrict__ hs, float* __restrict__ hfin)
{
    __shared__ unsigned short h_lds[2][16 * 256];   // swizzled bf16, dbuf

    const int tid  = threadIdx.x;
    const int w    = tid >> 6, lane = tid & 63;
    const int l15  = lane & 15, lhi = lane >> 4;
    const int lhi4 = lhi * 4;
    const int b0   = blockIdx.x * 16;
    const int hb0  = w * 32, hb1 = hb0 + 16;
    char* ldsbase  = (char*)&h_lds[0][0];

    // swizzle: byte (row,c2) -> row*512 + (c2 ^ ((row&7)<<4))
    const unsigned swzm = (unsigned)((l15 & 7) << 4);
    // read base: addr(kt,cb) = rb2 ^ ((kt<<6) | (cb<<13))
    const unsigned rb2 = (unsigned)(l15 * 512)
                       + ((unsigned)(lhi * 16) ^ (swzm & 0x30u))
                       + (swzm & 0x40u);
    // write addrs (buf0-based; hb0*2+lhi*8 has bit5==0 so hb1 = ^32)
    const unsigned wab  = (unsigned)(l15 * 512)
                        + (((unsigned)(hb0 * 2 + lhi * 8)) ^ swzm);
    const unsigned wab1 = wab ^ 32u;

    // persistent A-fragments (prescaled W_hh^T)
    bf16x8 afrag0[8], afrag1[8];
    #pragma unroll
    for (int kt = 0; kt < 8; ++kt) {
        afrag0[kt] = *(const bf16x8*)(whhT16 + (hb0 + l15) * H_ + kt * 32 + lhi * 8);
        afrag1[kt] = *(const bf16x8*)(whhT16 + (hb1 + l15) * H_ + kt * 32 + lhi * 8);
    }

    // init h buffer 0 from `hidden` (same swizzle)
    for (int i = tid; i < 16 * 256; i += 512) {
        int row = i >> 8, c = i & 255;
        *(unsigned short*)(ldsbase + (row * 512 + ((c * 2) ^ ((row & 7) << 4)))) =
            f2bf(hidden[(b0 + row) * H_ + c]);
    }

    // pipelined gather state
    const char* e8 = (const char*)embW2;
    const unsigned go = (unsigned)((hb0 + lhi4) * 4);
    const int* xp = x + (b0 + l15) * L_ + 2;
    char* hsp = (char*)hs + (size_t)(b0 + l15) * L_ * (H_ * 2) + (hb0 + lhi4) * 2;

    int xvA = x[(b0 + l15) * L_ + 0];
    unsigned v0 = ((unsigned)xvA << 10) + go;
    f32x4 eA0 = *(const f32x4*)(e8 + v0);
    f32x4 eA1 = *(const f32x4*)(e8 + v0 + 64);
    int xvB = x[(b0 + l15) * L_ + 1];
    f32x4 eB0, eB1;

    __syncthreads();

    auto phase = [&](f32x4& ec0, f32x4& ec1, f32x4& en0, f32x4& en1,
                     int xg, int& xf, int CB, bool PG, bool PX, bool FIN)
                     __attribute__((always_inline)) {
        // 1. issue next-step gathers FIRST (before any stores: in-order vmcnt)
        if (PG) {
            unsigned vo = ((unsigned)xg << 10) + go;
            en0 = *(const f32x4*)(e8 + vo);
            en1 = *(const f32x4*)(e8 + vo + 64);
        }
        if (PX) { xf = *xp; ++xp; }

        // 2. LDS reads (one v_xor each) + two independent MFMA chains
        bf16x8 hv[8];
        #pragma unroll
        for (int kt = 0; kt < 8; ++kt)
            hv[kt] = *(const bf16x8*)(ldsbase +
                       (rb2 ^ (unsigned)((kt << 6) | (CB << 13))));
        f32x4 acc0 = ec0, acc1 = ec1;
        #pragma unroll
        for (int kt = 0; kt < 8; ++kt)
            acc0 = __builtin_amdgcn_mfma_f32_16x16x32_bf16(afrag0[kt], hv[kt], acc0, 0, 0, 0);
        #pragma unroll
        for (int kt = 0; kt < 8; ++kt)
            acc1 = __builtin_amdgcn_mfma_f32_16x16x32_bf16(afrag1[kt], hv[kt], acc1, 0, 0, 0);

        // 3. tanh (input pre-scaled): th = 1 - 2/(exp2(acc)+1)
        f32x4 th0, th1;
        #pragma unroll
        for (int r = 0; r < 4; ++r) {
            float e = __builtin_exp2f(acc0[r]);
            th0[r] = 1.0f - 2.0f * __builtin_amdgcn_rcpf(e + 1.0f);
        }
        uint2 p0, p1;
        asm("v_cvt_pk_bf16_f32 %0, %1, %2" : "=v"(p0.x) : "v"(th0[0]), "v"(th0[1]));
        asm("v_cvt_pk_bf16_f32 %0, %1, %2" : "=v"(p0.y) : "v"(th0[2]), "v"(th0[3]));
        #pragma unroll
        for (int r = 0; r < 4; ++r) {
            float e = __builtin_exp2f(acc1[r]);
            th1[r] = 1.0f - 2.0f * __builtin_amdgcn_rcpf(e + 1.0f);
        }
        asm("v_cvt_pk_bf16_f32 %0, %1, %2" : "=v"(p1.x) : "v"(th1[0]), "v"(th1[1]));
        asm("v_cvt_pk_bf16_f32 %0, %1, %2" : "=v"(p1.y) : "v"(th1[2]), "v"(th1[3]));

        // 4. h -> other LDS buffer (precomputed addrs)
        *(uint2*)(ldsbase + (wab  + ((CB ^ 1) << 13))) = p0;
        *(uint2*)(ldsbase + (wab1 + ((CB ^ 1) << 13))) = p1;

        // 5. hs stores (fire-and-forget, after gathers in program order)
        *(uint2*)hsp = p0;
        *(uint2*)(hsp + 32) = p1;
        hsp += 512;

        if (FIN) {
            *(f32x4*)(hfin + (b0 + l15) * H_ + hb0 + lhi4) = th0;
            *(f32x4*)(hfin + (b0 + l15) * H_ + hb1 + lhi4) = th1;
        }

        // 6. LDS-only barrier (global stores stay in flight)
        __builtin_amdgcn_sched_barrier(0);
        asm volatile("s_waitcnt lgkmcnt(0)" ::: "memory");
        __builtin_amdgcn_s_barrier();
        __builtin_amdgcn_sched_barrier(0);
    };

    // t = 0..509 (both phases prefetch gather + x)
    for (int i = 0; i < 255; ++i) {
        phase(eA0, eA1, eB0, eB1, xvB, xvA, 0, true, true, false);
        phase(eB0, eB1, eA0, eA1, xvA, xvB, 1, true, true, false);
    }
    // t = 510: gather for 511 (xg = x[511]), no x-load
    phase(eA0, eA1, eB0, eB1, xvB, xvA, 0, true, false, false);
    // t = 511: no prefetch, write final hidden
    phase(eB0, eB1, eA0, eA1, 0, xvB, 1, false, false, true);
}

// ---------------- logits: hs[65536,256] @ W_hy^T + bias -------------------
__global__ __launch_bounds__(256, 1) void logits_kernel(
    const unsigned short* __restrict__ hs,
    const unsigned short* __restrict__ whyb16,
    const float* __restrict__ bias,
    float* __restrict__ logits)
{
    __shared__ unsigned short a_lds[2][32 * 256];   // 2 x 16KB, swizzled

    const int tid = threadIdx.x;
    const int w = tid >> 6, lane = tid & 63;
    const int l15 = lane & 15, lhi = lane >> 4;
    const size_t rowblk = (size_t)blockIdx.x * 256;

    int col[4];
    #pragma unroll
    for (int n = 0; n < 4; ++n) col[n] = w * 64 + n * 16 + l15;

    bf16x8 bfrag[4][8];
    #pragma unroll
    for (int n = 0; n < 4; ++n)
        #pragma unroll
        for (int kt = 0; kt < 8; ++kt)
            bfrag[n][kt] = *(const bf16x8*)(whyb16 + col[n] * H_ + kt * 32 + lhi * 8);

    float bv[4];
    #pragma unroll
    for (int n = 0; n < 4; ++n) bv[n] = bias[col[n]];

    auto swz = [](unsigned row, unsigned inrow) -> unsigned {
        return row * 512u + (inrow ^ ((row & 7u) << 4));
    };

    #pragma unroll
    for (int ii = 0; ii < 4; ++ii) {
        unsigned Lg = (unsigned)(ii * 256 + tid) * 16u;
        unsigned row = Lg >> 9, inrow = Lg & 511u;
        ushort8 v = *(const ushort8*)((const char*)hs +
                     ((rowblk + row) * 512u + inrow));
        *(ushort8*)((char*)a_lds[0] + swz(row, inrow)) = v;
    }
    __syncthreads();

    for (int c = 0; c < 8; ++c) {
        const int cb = c & 1;
        ushort8 vs[4];
        unsigned srow[4], sinrow[4];
        if (c < 7) {
            #pragma unroll
            for (int ii = 0; ii < 4; ++ii) {
                unsigned Lg = (unsigned)(ii * 256 + tid) * 16u;
                srow[ii] = Lg >> 9; sinrow[ii] = Lg & 511u;
                vs[ii] = *(const ushort8*)((const char*)hs +
                          ((rowblk + (size_t)(c + 1) * 32 + srow[ii]) * 512u + sinrow[ii]));
            }
        }

        #pragma unroll
        for (int m = 0; m < 2; ++m) {
            f32x4 acc[4];
            #pragma unroll
            for (int n = 0; n < 4; ++n) acc[n] = f32x4{0.f, 0.f, 0.f, 0.f};
            #pragma unroll
            for (int kt = 0; kt < 8; ++kt) {
                unsigned rl = (unsigned)(m * 16 + l15);
                bf16x8 a = *(const bf16x8*)((const char*)a_lds[cb] +
                            swz(rl, (unsigned)(kt * 64 + lhi * 16)));
                #pragma unroll
                for (int n = 0; n < 4; ++n)
                    acc[n] = __builtin_amdgcn_mfma_f32_16x16x32_bf16(
                                 a, bfrag[n][kt], acc[n], 0, 0, 0);
            }
            size_t grow = rowblk + (size_t)c * 32 + m * 16 + lhi * 4;
            #pragma unroll
            for (int n = 0; n < 4; ++n)
                #pragma unroll
                for (int r = 0; r < 4; ++r)
                    logits[(grow + r) * V_ + col[n]] = acc[n][r] + bv[n];
        }
        if (c < 7) {
            #pragma unroll
            for (int ii = 0; ii < 4; ++ii)
                *(ushort8*)((char*)a_lds[cb ^ 1] + swz(srow[ii], sinrow[ii])) = vs[ii];
        }
        __syncthreads();
    }
}

extern "C" void kernel_launch(void* const* d_in, const int* in_sizes, int n_in,
                              void* d_out, int out_size, void* d_ws, size_t ws_size,
                              hipStream_t stream) {
    const int*   x      = (const int*)d_in[0];
    const float* hidden = (const float*)d_in[1];
    const float* emb    = (const float*)d_in[2];
    const float* Wxh    = (const float*)d_in[3];
    const float* Whh    = (const float*)d_in[4];
    const float* bh     = (const float*)d_in[5];
    const float* Why    = (const float*)d_in[6];
    const float* Whyb   = (const float*)d_in[7];
    const float* by     = (const float*)d_in[8];

    float* out = (float*)d_out;
    char*  ws  = (char*)d_ws;

    unsigned short* hs     = (unsigned short*)ws;                  // 33,554,432 B
    float*          embW2  = (float*)(ws + 33554432);              //    262,144 B
    unsigned short* whyb16 = (unsigned short*)(ws + 33816576);     //    131,072 B
    float*          bias   = (float*)(ws + 33947648);              //      1,024 B
    unsigned short* whhT16 = (unsigned short*)(ws + 33948672);     //    131,072 B

    prologue_kernel<<<2 * V_ + 1 + V_, 256, 0, stream>>>(emb, Wxh, bh, Why, Whyb, by, Whh,
                                                         embW2, whyb16, bias, whhT16);
    rnn_rec_kernel<<<B_ / 16, 512, 0, stream>>>(x, hidden, embW2, whhT16,
                                                hs, out + (size_t)B_ * L_ * V_);
    logits_kernel<<<(B_ * L_) / 256, 256, 0, stream>>>(hs, whyb16, bias, out);
}

// Round 4
// 454.165 us; speedup vs baseline: 1.3316x; 1.0685x over previous
//
#include <hip/hip_runtime.h>
#include <hip/hip_bf16.h>
#include <stdint.h>

#define B_ 128
#define L_ 512
#define V_ 256
#define E_ 64
#define H_ 256
#define SC 2.885390081777927f   // 2*log2(e): exp2(SC*z) = e^{2z}

typedef __attribute__((ext_vector_type(8))) __bf16 bf16x8;
typedef __attribute__((ext_vector_type(4))) float f32x4;
typedef __attribute__((ext_vector_type(8))) unsigned short ushort8;

__device__ __forceinline__ unsigned short f2bf(float f) {
    unsigned int u = __builtin_bit_cast(unsigned int, f);
    u += 0x7fffu + ((u >> 16) & 1u);           // RNE
    return (unsigned short)(u >> 16);
}

// ---------------- prologue: embW2 = SC*(emb@W_xh + b_h) ; casts; bias -----
__global__ void prologue_kernel(const float* __restrict__ emb,
                                const float* __restrict__ Wxh,
                                const float* __restrict__ bh,
                                const float* __restrict__ Why,
                                const float* __restrict__ Whyb,
                                const float* __restrict__ by,
                                const float* __restrict__ Whh,
                                float* __restrict__ embW2,
                                unsigned short* __restrict__ whyb16,
                                float* __restrict__ bias,
                                unsigned short* __restrict__ whhT16)
{
    int blk = blockIdx.x, tid = threadIdx.x;
    if (blk < V_) {
        float s = bh[tid];
        #pragma unroll 8
        for (int e = 0; e < E_; ++e)
            s = fmaf(emb[blk * E_ + e], Wxh[e * H_ + tid], s);
        embW2[blk * H_ + tid] = s * SC;
    } else if (blk < 2 * V_) {
        int i = (blk - V_) * 256 + tid;
        whyb16[i] = f2bf(Why[i]);
    } else if (blk == 2 * V_) {
        bias[tid] = Whyb[tid] + by[tid];
    } else {
        int c = blk - (2 * V_ + 1);                       // hcol
        whhT16[c * H_ + tid] = f2bf(Whh[tid * H_ + c] * SC);  // SC*W_hh^T
    }
}

// ---------------- recurrence: 8 blocks x 16 batch rows, 512 steps ---------
// 4 waves x 64 hcols each (4 fragments). z^T = (SC*W_hh^T) @ h^T.
// D layout (m89): lane(lhi,l15) -> batch=l15, hcol = hb_f + lhi*4 + r.
__global__ __launch_bounds__(256, 1) void rnn_rec_kernel(
    const int* __restrict__ x, const float* __restrict__ hidden,
    const float* __restrict__ embW2, const unsigned short* __restrict__ whhT16,
    unsigned short* __restrict__ hs, float* __restrict__ hfin)
{
    __shared__ unsigned short h_lds[2][16 * 256];   // swizzled bf16, dbuf

    const int tid  = threadIdx.x;
    const int w    = tid >> 6, lane = tid & 63;
    const int l15  = lane & 15, lhi = lane >> 4;
    const int lhi4 = lhi * 4;
    const int b0   = blockIdx.x * 16;
    char* ldsbase  = (char*)&h_lds[0][0];

    // swizzle: byte (row,c2) -> row*512 + (c2 ^ ((row&7)<<4))
    const unsigned swzm = (unsigned)((l15 & 7) << 4);
    // read base: addr(kt,cb) = rb2 ^ ((kt<<6) | (cb<<13))
    const unsigned rb2 = (unsigned)(l15 * 512)
                       + ((unsigned)(lhi * 16) ^ (swzm & 0x30u))
                       + (swzm & 0x40u);
    // write base for fragment f: wab0 ^ (f<<5)  (bits 5-6 enter purely by XOR)
    const unsigned wab0 = (unsigned)(l15 * 512)
                        + (unsigned)(w * 128)
                        + (((unsigned)(lhi * 8)) ^ (swzm & 0x10u))
                        + (swzm & 0x60u);

    // persistent A-fragments (prescaled W_hh^T): f=0..3 -> hcols w*64+f*16+..
    bf16x8 afrag[4][8];
    #pragma unroll
    for (int f = 0; f < 4; ++f)
        #pragma unroll
        for (int kt = 0; kt < 8; ++kt)
            afrag[f][kt] = *(const bf16x8*)(whhT16 +
                (w * 64 + f * 16 + l15) * H_ + kt * 32 + lhi * 8);

    // init h buffer 0 from `hidden` (same swizzle)
    for (int i = tid; i < 16 * 256; i += 256) {
        int row = i >> 8, c = i & 255;
        *(unsigned short*)(ldsbase + (row * 512 + ((c * 2) ^ ((row & 7) << 4)))) =
            f2bf(hidden[(b0 + row) * H_ + c]);
    }

    // pipelined gather state
    const char* e8 = (const char*)embW2;
    const unsigned go = (unsigned)((w * 64 + lhi4) * 4);   // + f*64 bytes
    const int* xp = x + (b0 + l15) * L_ + 2;
    char* hsp = (char*)hs + (size_t)(b0 + l15) * L_ * (H_ * 2) + (w * 64 + lhi4) * 2;

    int xvA = x[(b0 + l15) * L_ + 0];
    f32x4 eA[4], eB[4];
    {
        unsigned v0 = ((unsigned)xvA << 10) + go;
        #pragma unroll
        for (int f = 0; f < 4; ++f)
            eA[f] = *(const f32x4*)(e8 + v0 + f * 64);
    }
    int xvB = x[(b0 + l15) * L_ + 1];

    __syncthreads();

    auto phase = [&](f32x4 (&ec)[4], f32x4 (&en)[4],
                     int xg, int& xf, int CB, bool PG, bool PX, bool FIN)
                     __attribute__((always_inline)) {
        // 1. issue next-step gathers FIRST (before stores: in-order vmcnt)
        if (PG) {
            unsigned vo = ((unsigned)xg << 10) + go;
            #pragma unroll
            for (int f = 0; f < 4; ++f)
                en[f] = *(const f32x4*)(e8 + vo + f * 64);
        }
        if (PX) { xf = *xp; ++xp; }

        // 2. LDS reads: full h tile as B-operand (shared by all 4 chains)
        bf16x8 hv[8];
        #pragma unroll
        for (int kt = 0; kt < 8; ++kt)
            hv[kt] = *(const bf16x8*)(ldsbase +
                       (rb2 ^ (unsigned)((kt << 6) | (CB << 13))));

        f32x4 acc[4];
        #pragma unroll
        for (int f = 0; f < 4; ++f) acc[f] = ec[f];

        f32x4 th[4];
        uint2 p[4];

        // 3. chain f0 first; then chain f+1 emitted alongside tanh(f):
        //    the MFMA pipe and VALU/trans pipe overlap within the wave.
        #pragma unroll
        for (int kt = 0; kt < 8; ++kt)
            acc[0] = __builtin_amdgcn_mfma_f32_16x16x32_bf16(afrag[0][kt], hv[kt], acc[0], 0, 0, 0);

        #pragma unroll
        for (int f = 0; f < 4; ++f) {
            if (f < 3) {
                #pragma unroll
                for (int kt = 0; kt < 8; ++kt)
                    acc[f + 1] = __builtin_amdgcn_mfma_f32_16x16x32_bf16(
                                     afrag[f + 1][kt], hv[kt], acc[f + 1], 0, 0, 0);
            }
            // tanh(acc[f]) (input pre-scaled): th = 1 - 2/(exp2(acc)+1)
            #pragma unroll
            for (int r = 0; r < 4; ++r) {
                float e = __builtin_exp2f(acc[f][r]);
                th[f][r] = 1.0f - 2.0f * __builtin_amdgcn_rcpf(e + 1.0f);
            }
            asm("v_cvt_pk_bf16_f32 %0, %1, %2" : "=v"(p[f].x) : "v"(th[f][0]), "v"(th[f][1]));
            asm("v_cvt_pk_bf16_f32 %0, %1, %2" : "=v"(p[f].y) : "v"(th[f][2]), "v"(th[f][3]));
            // h chunk f -> other LDS buffer
            *(uint2*)(ldsbase + ((wab0 ^ (unsigned)(f << 5)) + ((CB ^ 1) << 13))) = p[f];
            // hs chunk f (fire-and-forget)
            *(uint2*)(hsp + f * 32) = p[f];
        }
        hsp += 512;

        if (FIN) {
            #pragma unroll
            for (int f = 0; f < 4; ++f)
                *(f32x4*)(hfin + (b0 + l15) * H_ + w * 64 + f * 16 + lhi4) = th[f];
        }

        // 4. LDS-only barrier (global stores stay in flight)
        __builtin_amdgcn_sched_barrier(0);
        asm volatile("s_waitcnt lgkmcnt(0)" ::: "memory");
        __builtin_amdgcn_s_barrier();
        __builtin_amdgcn_sched_barrier(0);
    };

    // t = 0..509 (both phases prefetch gather + x)
    for (int i = 0; i < 255; ++i) {
        phase(eA, eB, xvB, xvA, 0, true, true, false);
        phase(eB, eA, xvA, xvB, 1, true, true, false);
    }
    // t = 510: gather for 511 (xg = x[511]), no x-load
    phase(eA, eB, xvB, xvA, 0, true, false, false);
    // t = 511: no prefetch, write final hidden
    phase(eB, eA, 0, xvB, 1, false, false, true);
}

// ---------------- logits: hs[65536,256] @ W_hy^T + bias -------------------
__global__ __launch_bounds__(256, 1) void logits_kernel(
    const unsigned short* __restrict__ hs,
    const unsigned short* __restrict__ whyb16,
    const float* __restrict__ bias,
    float* __restrict__ logits)
{
    __shared__ unsigned short a_lds[2][32 * 256];   // 2 x 16KB, swizzled

    const int tid = threadIdx.x;
    const int w = tid >> 6, lane = tid & 63;
    const int l15 = lane & 15, lhi = lane >> 4;
    const size_t rowblk = (size_t)blockIdx.x * 256;

    int col[4];
    #pragma unroll
    for (int n = 0; n < 4; ++n) col[n] = w * 64 + n * 16 + l15;

    bf16x8 bfrag[4][8];
    #pragma unroll
    for (int n = 0; n < 4; ++n)
        #pragma unroll
        for (int kt = 0; kt < 8; ++kt)
            bfrag[n][kt] = *(const bf16x8*)(whyb16 + col[n] * H_ + kt * 32 + lhi * 8);

    float bv[4];
    #pragma unroll
    for (int n = 0; n < 4; ++n) bv[n] = bias[col[n]];

    auto swz = [](unsigned row, unsigned inrow) -> unsigned {
        return row * 512u + (inrow ^ ((row & 7u) << 4));
    };

    #pragma unroll
    for (int ii = 0; ii < 4; ++ii) {
        unsigned Lg = (unsigned)(ii * 256 + tid) * 16u;
        unsigned row = Lg >> 9, inrow = Lg & 511u;
        ushort8 v = *(const ushort8*)((const char*)hs +
                     ((rowblk + row) * 512u + inrow));
        *(ushort8*)((char*)a_lds[0] + swz(row, inrow)) = v;
    }
    __syncthreads();

    for (int c = 0; c < 8; ++c) {
        const int cb = c & 1;
        ushort8 vs[4];
        unsigned srow[4], sinrow[4];
        if (c < 7) {
            #pragma unroll
            for (int ii = 0; ii < 4; ++ii) {
                unsigned Lg = (unsigned)(ii * 256 + tid) * 16u;
                srow[ii] = Lg >> 9; sinrow[ii] = Lg & 511u;
                vs[ii] = *(const ushort8*)((const char*)hs +
                          ((rowblk + (size_t)(c + 1) * 32 + srow[ii]) * 512u + sinrow[ii]));
            }
        }

        #pragma unroll
        for (int m = 0; m < 2; ++m) {
            f32x4 acc[4];
            #pragma unroll
            for (int n = 0; n < 4; ++n) acc[n] = f32x4{0.f, 0.f, 0.f, 0.f};
            #pragma unroll
            for (int kt = 0; kt < 8; ++kt) {
                unsigned rl = (unsigned)(m * 16 + l15);
                bf16x8 a = *(const bf16x8*)((const char*)a_lds[cb] +
                            swz(rl, (unsigned)(kt * 64 + lhi * 16)));
                #pragma unroll
                for (int n = 0; n < 4; ++n)
                    acc[n] = __builtin_amdgcn_mfma_f32_16x16x32_bf16(
                                 a, bfrag[n][kt], acc[n], 0, 0, 0);
            }
            size_t grow = rowblk + (size_t)c * 32 + m * 16 + lhi * 4;
            #pragma unroll
            for (int n = 0; n < 4; ++n)
                #pragma unroll
                for (int r = 0; r < 4; ++r)
                    logits[(grow + r) * V_ + col[n]] = acc[n][r] + bv[n];
        }
        if (c < 7) {
            #pragma unroll
            for (int ii = 0; ii < 4; ++ii)
                *(ushort8*)((char*)a_lds[cb ^ 1] + swz(srow[ii], sinrow[ii])) = vs[ii];
        }
        __syncthreads();
    }
}

extern "C" void kernel_launch(void* const* d_in, const int* in_sizes, int n_in,
                              void* d_out, int out_size, void* d_ws, size_t ws_size,
                              hipStream_t stream) {
    const int*   x      = (const int*)d_in[0];
    const float* hidden = (const float*)d_in[1];
    const float* emb    = (const float*)d_in[2];
    const float* Wxh    = (const float*)d_in[3];
    const float* Whh    = (const float*)d_in[4];
    const float* bh     = (const float*)d_in[5];
    const float* Why    = (const float*)d_in[6];
    const float* Whyb   = (const float*)d_in[7];
    const float* by     = (const float*)d_in[8];

    float* out = (float*)d_out;
    char*  ws  = (char*)d_ws;

    unsigned short* hs     = (unsigned short*)ws;                  // 33,554,432 B
    float*          embW2  = (float*)(ws + 33554432);              //    262,144 B
    unsigned short* whyb16 = (unsigned short*)(ws + 33816576);     //    131,072 B
    float*          bias   = (float*)(ws + 33947648);              //      1,024 B
    unsigned short* whhT16 = (unsigned short*)(ws + 33948672);     //    131,072 B

    prologue_kernel<<<2 * V_ + 1 + V_, 256, 0, stream>>>(emb, Wxh, bh, Why, Whyb, by, Whh,
                                                         embW2, whyb16, bias, whhT16);
    rnn_rec_kernel<<<B_ / 16, 256, 0, stream>>>(x, hidden, embW2, whhT16,
                                                hs, out + (size_t)B_ * L_ * V_);
    logits_kernel<<<(B_ * L_) / 256, 256, 0, stream>>>(hs, whyb16, bias, out);
}